// Round 1
// baseline (54357.935 us; speedup 1.0000x reference)
//
#include <hip/hip_runtime.h>
#include <hip/hip_bf16.h>
#include <math.h>

#define BATCH 64
#define HID   1024
#define SEQ   256
#define KTOT  2048   // 1024 (x) + 1024 (h)
#define KC    128

// ---------------------------------------------------------------------------
// init: copy h0/c0 into workspace ping-pong buffers
// ---------------------------------------------------------------------------
__global__ __launch_bounds__(256) void init_hc(
    const float* __restrict__ h0, const float* __restrict__ c0,
    float* __restrict__ h, float* __restrict__ c)
{
    int i = blockIdx.x * 256 + threadIdx.x;
    if (i < BATCH * HID) { h[i] = h0[i]; c[i] = c0[i]; }
}

// ---------------------------------------------------------------------------
// final: write h_fin / c_fin into the output tail
// ---------------------------------------------------------------------------
__global__ __launch_bounds__(256) void write_final(
    const float* __restrict__ h, const float* __restrict__ c,
    float* __restrict__ out_h, float* __restrict__ out_c)
{
    int i = blockIdx.x * 256 + threadIdx.x;
    if (i < BATCH * HID) { out_h[i] = h[i]; out_c[i] = c[i]; }
}

// ---------------------------------------------------------------------------
// one LSTM timestep, fused x-projection + h-projection + cell.
// grid: 256 blocks, block j owns output columns [4j, 4j+4) for ALL 64 batches.
// block: 256 threads; thread = (b = tid&63, r = tid>>6); computes the 4 gate
// quarters {q*HID + 4*blk + r} so the cell update is thread-local.
// ---------------------------------------------------------------------------
__global__ __launch_bounds__(256) void lstm_step(
    const int*   __restrict__ tgt,    // [B, SEQ] (int32 from harness)
    const float* __restrict__ emb,    // [VOCAB, HID]
    const float* __restrict__ W_ih,   // [4*HID, HID]
    const float* __restrict__ W_hh,   // [4*HID, HID]
    const float* __restrict__ b_ih,   // [4*HID]
    const float* __restrict__ b_hh,   // [4*HID]
    const float* __restrict__ h_in,   // [B, HID]
    const float* __restrict__ c_in,   // [B, HID]
    float* __restrict__ h_out,
    float* __restrict__ c_out,
    float* __restrict__ outputs,      // [B, SEQ, HID]
    int t)
{
    __shared__ float xh[BATCH][KC + 1];   // +1 pad: lanes hit 2/bank (free)
    __shared__ float w[16][KC + 1];
    __shared__ int   tgtrow[BATCH];

    const int tid = threadIdx.x;
    const int j0  = blockIdx.x * 4;
    const int b   = tid & 63;
    const int r   = tid >> 6;            // 0..3

    if (tid < BATCH) tgtrow[tid] = tgt[tid * SEQ + t];

    float acc[4];
    #pragma unroll
    for (int q = 0; q < 4; ++q) {
        int n = q * HID + j0 + r;
        acc[q] = b_ih[n] + b_hh[n];
    }
    __syncthreads();

    for (int kc = 0; kc < KTOT; kc += KC) {
        // stage xh chunk: 64 x 128 floats (x = emb[tgt] for k<HID, else h_in)
        #pragma unroll
        for (int i = 0; i < (BATCH * KC) / 256; ++i) {
            int fi = i * 256 + tid;
            int bl = fi >> 7;
            int kk = fi & (KC - 1);
            int k  = kc + kk;
            float v;
            if (k < HID) v = emb[(size_t)tgtrow[bl] * HID + k];
            else         v = h_in[bl * HID + (k - HID)];
            xh[bl][kk] = v;
        }
        // stage W chunk: 16 gate-rows x 128 (rows q*HID + j0 + rr)
        #pragma unroll
        for (int i = 0; i < (16 * KC) / 256; ++i) {
            int fi = i * 256 + tid;
            int ri = fi >> 7;
            int kk = fi & (KC - 1);
            int q  = ri >> 2, rr = ri & 3;
            int n  = q * HID + j0 + rr;
            int k  = kc + kk;
            float v;
            if (k < HID) v = W_ih[(size_t)n * HID + k];
            else         v = W_hh[(size_t)n * HID + (k - HID)];
            w[ri][kk] = v;
        }
        __syncthreads();

        #pragma unroll 4
        for (int kk = 0; kk < KC; ++kk) {
            float xv = xh[b][kk];          // lanes: distinct b, 2/bank, free
            #pragma unroll
            for (int q = 0; q < 4; ++q)    // w[...] is a wave-broadcast read
                acc[q] = fmaf(xv, w[q * 4 + r][kk], acc[q]);
        }
        __syncthreads();
    }

    // LSTM cell (gate order i, f, g, o — PyTorch layout)
    float ig = 1.f / (1.f + __expf(-acc[0]));
    float fg = 1.f / (1.f + __expf(-acc[1]));
    float gg = tanhf(acc[2]);
    float og = 1.f / (1.f + __expf(-acc[3]));

    int   j     = j0 + r;
    float cprev = c_in[b * HID + j];
    float cnew  = fg * cprev + ig * gg;
    float hnew  = og * tanhf(cnew);

    c_out[b * HID + j] = cnew;
    h_out[b * HID + j] = hnew;
    outputs[((size_t)b * SEQ + t) * HID + j] = hnew;
}

// ---------------------------------------------------------------------------
extern "C" void kernel_launch(void* const* d_in, const int* in_sizes, int n_in,
                              void* d_out, int out_size, void* d_ws, size_t ws_size,
                              hipStream_t stream)
{
    const int*   tgt = (const int*)  d_in[0];
    const float* h0  = (const float*)d_in[1];
    const float* c0  = (const float*)d_in[2];
    // d_in[3] encoder_outputs, d_in[4] src_lengths: unused in the math
    const float* emb = (const float*)d_in[5];
    const float* Wih = (const float*)d_in[6];
    const float* Whh = (const float*)d_in[7];
    const float* bih = (const float*)d_in[8];
    const float* bhh = (const float*)d_in[9];

    float* out      = (float*)d_out;
    float* outputs  = out;                                   // [B,SEQ,HID]
    float* out_h    = out + (size_t)BATCH * SEQ * HID;
    float* out_c    = out_h + BATCH * HID;

    float* ws = (float*)d_ws;
    float* hb[2] = { ws,                ws + BATCH * HID };
    float* cb[2] = { ws + 2 * BATCH * HID, ws + 3 * BATCH * HID };

    init_hc<<<(BATCH * HID) / 256, 256, 0, stream>>>(h0, c0, hb[0], cb[0]);

    for (int t = 0; t < SEQ; ++t) {
        lstm_step<<<256, 256, 0, stream>>>(
            tgt, emb, Wih, Whh, bih, bhh,
            hb[t & 1], cb[t & 1], hb[(t + 1) & 1], cb[(t + 1) & 1],
            outputs, t);
    }

    // after t = SEQ-1, final state lives in buffer index SEQ & 1 == 0
    write_final<<<(BATCH * HID) / 256, 256, 0, stream>>>(
        hb[0], cb[0], out_h, out_c);
}

// Round 2
// 6714.996 us; speedup vs baseline: 8.0950x; 8.0950x over previous
//
#include <hip/hip_runtime.h>
#include <hip/hip_bf16.h>
#include <math.h>

#define B   64
#define T   256
#define H   1024
#define G4  4096
#define TC  64            // timesteps per x_proj chunk
#define NCH (T / TC)

typedef __attribute__((ext_vector_type(8))) short bf16x8;
typedef __attribute__((ext_vector_type(4))) float f32x4;

__device__ __forceinline__ unsigned short f2bf(float x) {
    union { float f; unsigned u; } v; v.f = x;
    unsigned r = v.u + 0x7fffu + ((v.u >> 16) & 1u);   // RNE
    return (unsigned short)(r >> 16);
}
__device__ __forceinline__ float bf2f(unsigned short s) {
    union { unsigned u; float f; } v; v.u = ((unsigned)s) << 16;
    return v.f;
}

// ---------------------------------------------------------------------------
// cast fp32 -> bf16, 8 elems/thread
// ---------------------------------------------------------------------------
__global__ __launch_bounds__(256) void cast_f32_bf16(
    const float* __restrict__ src, unsigned short* __restrict__ dst, int n8)
{
    int i = blockIdx.x * 256 + threadIdx.x;
    if (i >= n8) return;
    const float4* s = (const float4*)(src + (size_t)i * 8);
    float4 a = s[0], b = s[1];
    bf16x8 o;
    o[0] = f2bf(a.x); o[1] = f2bf(a.y); o[2] = f2bf(a.z); o[3] = f2bf(a.w);
    o[4] = f2bf(b.x); o[5] = f2bf(b.y); o[6] = f2bf(b.z); o[7] = f2bf(b.w);
    *(bf16x8*)(dst + (size_t)i * 8) = o;
}

// ---------------------------------------------------------------------------
// gather+cast one T-chunk of embeddings: xch[r = tc*B + b][k] = bf16(emb[tgt[b][t0+tc]][k])
// ---------------------------------------------------------------------------
__global__ __launch_bounds__(256) void gather_x(
    const int* __restrict__ tgt, const float* __restrict__ emb,
    unsigned short* __restrict__ xch, int t0)
{
    int tid = threadIdx.x;
    int r   = blockIdx.x * 2 + (tid >> 7);     // 0..4095
    int c   = (tid & 127) * 8;
    int b   = r & 63, tcc = r >> 6;
    int token = tgt[b * T + t0 + tcc];
    const float4* s = (const float4*)(emb + (size_t)token * H + c);
    float4 x0 = s[0], x1 = s[1];
    bf16x8 o;
    o[0] = f2bf(x0.x); o[1] = f2bf(x0.y); o[2] = f2bf(x0.z); o[3] = f2bf(x0.w);
    o[4] = f2bf(x1.x); o[5] = f2bf(x1.y); o[6] = f2bf(x1.z); o[7] = f2bf(x1.w);
    *(bf16x8*)(xch + (size_t)r * H + c) = o;
}

// ---------------------------------------------------------------------------
// x_proj chunk GEMM: C[4096][4096] bf16 = A[4096][1024] * Bt[4096][1024]^T
// 128x128 tile, 4 waves, 4x4 16x16x32 frags/wave, XOR-swizzled LDS (G4 fix).
// ---------------------------------------------------------------------------
__global__ __launch_bounds__(256) void gemm_xproj(
    const unsigned short* __restrict__ A,   // x chunk bf16
    const unsigned short* __restrict__ Bt,  // W_ih bf16 [N][K]
    unsigned short* __restrict__ C)
{
    __shared__ unsigned short As[128 * 64], Bs[128 * 64];
    const int tid  = threadIdx.x;
    const int brow = (blockIdx.x >> 5) * 128;
    const int bcol = (blockIdx.x & 31) * 128;
    const int w = tid >> 6, lane = tid & 63;
    const int wr = w >> 1, wc = w & 1;
    const int lr = lane & 15, lg = lane >> 4;

    f32x4 acc[4][4] = {};

    for (int kc = 0; kc < H; kc += 64) {
        if (kc) __syncthreads();
        #pragma unroll
        for (int i = 0; i < 4; ++i) {
            int sf  = i * 256 + tid;           // 0..1023 slots of 16B
            int row = sf >> 3, s = sf & 7;
            int col = kc + s * 8;
            *(bf16x8*)(As + row * 64 + ((s ^ (row & 7)) * 8)) =
                *(const bf16x8*)(A + (size_t)(brow + row) * H + col);
            *(bf16x8*)(Bs + row * 64 + ((s ^ (row & 7)) * 8)) =
                *(const bf16x8*)(Bt + (size_t)(bcol + row) * H + col);
        }
        __syncthreads();
        #pragma unroll
        for (int kk = 0; kk < 2; ++kk) {
            bf16x8 af[4], bv[4];
            #pragma unroll
            for (int m = 0; m < 4; ++m) {
                int row = wr * 64 + m * 16 + lr;
                int s   = kk * 4 + lg;
                af[m] = *(const bf16x8*)(As + row * 64 + ((s ^ (row & 7)) * 8));
            }
            #pragma unroll
            for (int n = 0; n < 4; ++n) {
                int row = wc * 64 + n * 16 + lr;
                int s   = kk * 4 + lg;
                bv[n] = *(const bf16x8*)(Bs + row * 64 + ((s ^ (row & 7)) * 8));
            }
            #pragma unroll
            for (int m = 0; m < 4; ++m)
                #pragma unroll
                for (int n = 0; n < 4; ++n)
                    acc[m][n] = __builtin_amdgcn_mfma_f32_16x16x32_bf16(
                        af[m], bv[n], acc[m][n], 0, 0, 0);
        }
    }
    #pragma unroll
    for (int m = 0; m < 4; ++m)
        #pragma unroll
        for (int n = 0; n < 4; ++n)
            #pragma unroll
            for (int r = 0; r < 4; ++r) {
                int row = brow + wr * 64 + m * 16 + lg * 4 + r;
                int col = bcol + wc * 64 + n * 16 + lr;
                C[(size_t)row * G4 + col] = f2bf(acc[m][n][r]);
            }
}

// ---------------------------------------------------------------------------
// one LSTM step: gates = h_bf16 @ W_hh^T (MFMA) + x_proj + bias, then cell.
// 64 blocks x 512 thr (8 waves). wave = (kh = K-half, q = gate). Each wave:
// 4 M-tiles x 1 N-tile x 16 k-steps. Partials reduced via padded LDS.
// ---------------------------------------------------------------------------
__global__ __launch_bounds__(512) void lstm_step(
    const unsigned short* __restrict__ xproj,  // [TC][B][4096] bf16
    const unsigned short* __restrict__ hin,    // [B][H] bf16
    const unsigned short* __restrict__ whh,    // [4096][1024] bf16
    const float* __restrict__ bih, const float* __restrict__ bhh,
    const float* __restrict__ cin, float* __restrict__ cout,
    unsigned short* __restrict__ hout,
    float* __restrict__ outputs, int t, int tc)
{
    __shared__ float red[2][4][64][17];
    const int tid = threadIdx.x;
    const int j0  = blockIdx.x * 16;
    const int w = tid >> 6, lane = tid & 63;
    const int kh = w & 1, q = w >> 1;
    const int lr = lane & 15, lg = lane >> 4;

    f32x4 acc[4] = {};
    const unsigned short* wrow = whh + (size_t)(q * H + j0 + lr) * H;
    #pragma unroll
    for (int ks = 0; ks < 16; ++ks) {
        int k0 = kh * 512 + ks * 32 + lg * 8;
        bf16x8 bq = *(const bf16x8*)(wrow + k0);
        #pragma unroll
        for (int m = 0; m < 4; ++m) {
            bf16x8 am = *(const bf16x8*)(hin + (size_t)(m * 16 + lr) * H + k0);
            acc[m] = __builtin_amdgcn_mfma_f32_16x16x32_bf16(am, bq, acc[m], 0, 0, 0);
        }
    }
    #pragma unroll
    for (int m = 0; m < 4; ++m)
        #pragma unroll
        for (int r = 0; r < 4; ++r)
            red[kh][q][m * 16 + lg * 4 + r][lr] = acc[m][r];
    __syncthreads();

    const int b  = tid & 63;
    const int jg = tid >> 6;                    // 0..7 -> 2 cols each
    #pragma unroll
    for (int jj = 0; jj < 2; ++jj) {
        int jc = jg * 2 + jj;
        int hj = j0 + jc;
        float g[4];
        #pragma unroll
        for (int qq = 0; qq < 4; ++qq) {
            int n = qq * H + hj;
            g[qq] = red[0][qq][b][jc] + red[1][qq][b][jc]
                  + bih[n] + bhh[n]
                  + bf2f(xproj[((size_t)tc * B + b) * G4 + n]);
        }
        float ig = 1.f / (1.f + expf(-g[0]));
        float fg = 1.f / (1.f + expf(-g[1]));
        float gg = tanhf(g[2]);
        float og = 1.f / (1.f + expf(-g[3]));
        float cp = cin[b * H + hj];
        float cn = fg * cp + ig * gg;
        float hn = og * tanhf(cn);
        cout[b * H + hj] = cn;
        hout[b * H + hj] = f2bf(hn);
        outputs[((size_t)b * T + t) * H + hj] = hn;
    }
}

// ---------------------------------------------------------------------------
__global__ __launch_bounds__(256) void init_state(
    const float* __restrict__ h0, const float* __restrict__ c0,
    unsigned short* __restrict__ hb, float* __restrict__ cb)
{
    int i = blockIdx.x * 256 + threadIdx.x;
    hb[i] = f2bf(h0[i]);
    cb[i] = c0[i];
}

__global__ __launch_bounds__(256) void finalize(
    const float* __restrict__ outputs, const float* __restrict__ cfin,
    float* __restrict__ outh, float* __restrict__ outc)
{
    int i = blockIdx.x * 256 + threadIdx.x;     // 0..65535
    int b = i >> 10, j = i & 1023;
    outh[i] = outputs[((size_t)b * T + (T - 1)) * H + j];
    outc[i] = cfin[i];
}

// ---------------------------------------------------------------------------
extern "C" void kernel_launch(void* const* d_in, const int* in_sizes, int n_in,
                              void* d_out, int out_size, void* d_ws, size_t ws_size,
                              hipStream_t stream)
{
    const int*   tgt = (const int*)  d_in[0];
    const float* h0  = (const float*)d_in[1];
    const float* c0  = (const float*)d_in[2];
    const float* emb = (const float*)d_in[5];
    const float* Wih = (const float*)d_in[6];
    const float* Whh = (const float*)d_in[7];
    const float* bih = (const float*)d_in[8];
    const float* bhh = (const float*)d_in[9];

    float* out     = (float*)d_out;
    float* outputs = out;                                  // [B][T][H]
    float* out_h   = out + (size_t)B * T * H;
    float* out_c   = out_h + B * H;

    // ws layout (bf16 then fp32) — ~59.5 MB total
    unsigned short* xproj = (unsigned short*)d_ws;          // TC*B*G4
    unsigned short* xch   = xproj + (size_t)TC * B * G4;    // (TC*B)*H
    unsigned short* wih   = xch   + (size_t)TC * B * H;     // G4*H
    unsigned short* whh   = wih   + (size_t)G4 * H;         // G4*H
    unsigned short* hb0   = whh   + (size_t)G4 * H;         // B*H
    unsigned short* hb1   = hb0   + (size_t)B * H;
    float*          cb0   = (float*)(hb1 + (size_t)B * H);
    float*          cb1   = cb0 + (size_t)B * H;

    cast_f32_bf16<<<2048, 256, 0, stream>>>(Wih, wih, (G4 * H) / 8);
    cast_f32_bf16<<<2048, 256, 0, stream>>>(Whh, whh, (G4 * H) / 8);
    init_state<<<(B * H) / 256, 256, 0, stream>>>(h0, c0, hb0, cb0);

    for (int ci = 0; ci < NCH; ++ci) {
        gather_x<<<(TC * B) / 2, 256, 0, stream>>>(tgt, emb, xch, ci * TC);
        gemm_xproj<<<(TC * B / 128) * (G4 / 128), 256, 0, stream>>>(xch, wih, xproj);
        for (int tcs = 0; tcs < TC; ++tcs) {
            int t = ci * TC + tcs;
            lstm_step<<<H / 16, 512, 0, stream>>>(
                xproj,
                (t & 1) ? hb1 : hb0, whh, bih, bhh,
                (t & 1) ? cb1 : cb0, (t & 1) ? cb0 : cb1,
                (t & 1) ? hb0 : hb1,
                outputs, t, tcs);
        }
    }
    finalize<<<(B * H) / 256, 256, 0, stream>>>(outputs, cb0, out_h, out_c);
}